// Round 3
// baseline (178.771 us; speedup 1.0000x reference)
//
#include <hip/hip_runtime.h>

// NormalizedCutLoss: N=4, C=32, H=W=256, ps=16 -> 1024 patches of 256 pixels.
// One block per patch. Thread t owns pixel i=t: f_i in registers, patch tile
// in LDS, j-loop over 256 pixels with broadcast LDS reads.

#define P2 256   // pixels per patch
#define CF 32    // feature channels

__global__ __launch_bounds__(256)
void ncut_loss_kernel(const float* __restrict__ pred,
                      const float* __restrict__ feat,
                      float* __restrict__ out)
{
    __shared__ float  fp_lds[P2][CF];   // 32 KB patch features
    __shared__ float2 sp_lds[P2];       // {sq, p} per pixel
    __shared__ float  red[8];

    const int b  = blockIdx.x;          // 0..1023 : patch id
    const int n  = b >> 8;              // batch
    const int l  = b & 255;             // patch within image
    const int hp = l >> 4;
    const int wp = l & 15;
    const int t  = threadIdx.x;         // pixel index within patch
    const int py = t >> 4, px = t & 15;
    const int row = hp * 16 + py;
    const int col = wp * 16 + px;

    // ---- load own pixel's features (kept in registers + staged to LDS) ----
    const float* fbase = feat + (((size_t)n * CF) * 256 + row) * 256 + col;
    float fi[CF];
    float sq = 0.f;
#pragma unroll
    for (int c = 0; c < CF; ++c) {
        float v = fbase[(size_t)c * 65536];   // stride H*W between channels
        fi[c] = v;
        fp_lds[t][c] = v;
        sq = fmaf(v, v, sq);
    }
    const float p_i = pred[((size_t)n * 256 + row) * 256 + col];
    sp_lds[t] = make_float2(sq, p_i);
    __syncthreads();

    // exponent constants:
    //   color:   -d_feat / (2*0.1^2)            = -50 * d_feat
    //   spatial: -(dpx^2+dpy^2)/255^2 / (2*16^2) = dsp_px2 * -1/(512*65025)
    const float CSP = -3.0036595e-8f;

    const float pyf = (float)py, pxf = (float)px;
    float api = 0.f;                      // Ap_i = sum_j A_ij p_j
    for (int j = 0; j < P2; ++j) {
        const float4* fj4 = (const float4*)(&fp_lds[j][0]);  // broadcast reads
        float d0 = 0.f, d1 = 0.f, d2 = 0.f, d3 = 0.f;
#pragma unroll
        for (int q = 0; q < 8; ++q) {
            float4 v = fj4[q];
            d0 = fmaf(fi[4*q+0], v.x, d0);
            d1 = fmaf(fi[4*q+1], v.y, d1);
            d2 = fmaf(fi[4*q+2], v.z, d2);
            d3 = fmaf(fi[4*q+3], v.w, d3);
        }
        float dot = (d0 + d1) + (d2 + d3);
        float2 sp = sp_lds[j];
        float dft = fmaxf(fmaf(-2.f, dot, sq + sp.x), 0.f);
        float dy = pyf - (float)(j >> 4);
        float dx = pxf - (float)(j & 15);
        float dsp = fmaf(dy, dy, dx * dx);
        float e = fmaf(dft, -50.f, dsp * CSP);
        api = fmaf(__expf(e), sp.y, api);
    }

    // ---- reduce: assoc = sum_i Ap_i ; cut = sum_i (1-p_i) Ap_i ----
    float assoc = api;
    float cut   = (1.f - p_i) * api;
#pragma unroll
    for (int off = 32; off > 0; off >>= 1) {
        assoc += __shfl_down(assoc, off);
        cut   += __shfl_down(cut,   off);
    }
    const int wave = t >> 6;
    if ((t & 63) == 0) { red[2*wave] = assoc; red[2*wave+1] = cut; }
    __syncthreads();
    if (t == 0) {
        float a = red[0] + red[2] + red[4] + red[6];
        float c = red[1] + red[3] + red[5] + red[7];
        atomicAdd(out, (c / (a + 1e-5f)) * (1.0f / 1024.0f));
    }
}

extern "C" void kernel_launch(void* const* d_in, const int* in_sizes, int n_in,
                              void* d_out, int out_size, void* d_ws, size_t ws_size,
                              hipStream_t stream)
{
    const float* pred = (const float*)d_in[0];   // (4,1,256,256) f32
    const float* feat = (const float*)d_in[1];   // (4,32,256,256) f32
    float* out = (float*)d_out;                  // scalar f32

    hipMemsetAsync(out, 0, sizeof(float) * out_size, stream);
    ncut_loss_kernel<<<1024, 256, 0, stream>>>(pred, feat, out);
}

// Round 4
// 119.595 us; speedup vs baseline: 1.4948x; 1.4948x over previous
//
#include <hip/hip_runtime.h>
#include <stdint.h>

// NormalizedCutLoss via MFMA: per patch (256 px, 32 ch), G = F*F^T with
// bf16 16x16x32 MFMA (K=32 in one instruction), diagonal forced exact,
// fused exp + p-weighted row reduce. One block (4 waves) per patch.

#define P2 256
#define CF 32
#define ROWP 40   // padded bf16 row length (32 data + 8 pad) -> 80B rows, 2-way banks

using bf16x8 = __attribute__((ext_vector_type(8))) short;
using f32x4  = __attribute__((ext_vector_type(4))) float;

__device__ __forceinline__ short f2bf(float x) {
    union { float f; uint32_t u; } v; v.f = x;
    uint32_t r = (v.u + 0x7FFFu + ((v.u >> 16) & 1u)) >> 16;   // RNE
    return (short)r;
}

__global__ __launch_bounds__(256)
void ncut_mfma_kernel(const float* __restrict__ pred,
                      const float* __restrict__ feat,
                      float* __restrict__ out)
{
    __shared__ short  fb[P2][ROWP];   // bf16 features, [pixel][channel]
    __shared__ float2 sp[P2];         // {sq(f32), p}
    __shared__ float  red[8];

    const int t  = threadIdx.x;
    const int l  = t & 63;
    const int w  = t >> 6;
    const int b  = blockIdx.x;
    const int n  = b >> 8, pl = b & 255;
    const int hp = pl >> 4, wp = pl & 15;
    const int py = t >> 4,  px = t & 15;
    const int row = hp * 16 + py, col = wp * 16 + px;

    // ---- stage: load 32 channels of own pixel, convert to bf16, sq in f32 ----
    const float* fbase = feat + (((size_t)n * CF) * 256 + row) * 256 + col;
    float sq = 0.f;
    short mybf[CF];
#pragma unroll
    for (int c = 0; c < CF; ++c) {
        float v = fbase[(size_t)c * 65536];
        sq = fmaf(v, v, sq);
        mybf[c] = f2bf(v);
    }
#pragma unroll
    for (int q = 0; q < 4; ++q)
        *(bf16x8*)&fb[t][q * 8] = *(const bf16x8*)&mybf[q * 8];
    const float p_i = pred[((size_t)n * 256 + row) * 256 + col];
    sp[t] = make_float2(sq, p_i);
    __syncthreads();

    // ---- fragments: lane l -> tile-row (l&15), k-block (l>>4)*8..+7 ----
    const int lr = l & 15;   // row/col within 16-tile
    const int lk = l >> 4;   // k-group
    bf16x8 bf[16];           // B-operand tiles (all 16 col-tiles), static idx
#pragma unroll
    for (int r = 0; r < 16; ++r)
        bf[r] = *(const bf16x8*)&fb[r * 16 + lr][lk * 8];
    bf16x8 af[4];            // A-operand tiles for this wave (runtime addr, static idx)
#pragma unroll
    for (int r = 0; r < 4; ++r)
        af[r] = *(const bf16x8*)&fb[(w * 4 + r) * 16 + lr][lk * 8];

    const float CSP = -3.0036595e-8f;    // -1/(2*16^2*255^2)
    const f32x4 zero = {0.f, 0.f, 0.f, 0.f};
    float assoc = 0.f, cut = 0.f;
    const float colpx = (float)lr;

#pragma unroll
    for (int tii = 0; tii < 4; ++tii) {
        const int ti = w * 4 + tii;
        float sqr[4], lx2[4], api[4];
        bool  dm[4];
#pragma unroll
        for (int r = 0; r < 4; ++r) {
            const int qi = lk * 4 + r;                 // row within tile
            float d = (float)qi - colpx;
            lx2[r] = d * d;
            sqr[r] = sp[ti * 16 + qi].x;
            dm[r]  = (qi == lr);
            api[r] = 0.f;
        }
#pragma unroll
        for (int tj = 0; tj < 16; ++tj) {
            f32x4 acc = __builtin_amdgcn_mfma_f32_16x16x32_bf16(af[tii], bf[tj], zero, 0, 0, 0);
            const float2 spc = sp[tj * 16 + lr];       // {sq_j, p_j}
            const float dyf = (float)(ti - tj);
            const float cs  = dyf * dyf * CSP;
            const bool tdiag = (ti == tj);
#pragma unroll
            for (int r = 0; r < 4; ++r) {
                float dft = fmaxf(fmaf(-2.f, acc[r], sqr[r] + spc.x), 0.f);
                float E   = fmaf(dft, -50.f, fmaf(lx2[r], CSP, cs));
                if (tdiag && dm[r]) E = 0.f;           // exact diagonal: A_ii = 1
                api[r] = fmaf(__expf(E), spc.y, api[r]);
            }
        }
        // reduce Ap over the 16 lanes sharing lk (they cover cols lr=0..15)
#pragma unroll
        for (int r = 0; r < 4; ++r) {
            float v = api[r];
            v += __shfl_xor(v, 1);
            v += __shfl_xor(v, 2);
            v += __shfl_xor(v, 4);
            v += __shfl_xor(v, 8);
            if (lr == 0) {
                const float2 s2 = sp[ti * 16 + lk * 4 + r];
                assoc += v;
                cut   += (1.f - s2.y) * v;
            }
        }
    }

    // ---- block reduce: loss_patch = cut / (assoc + eps) ----
#pragma unroll
    for (int off = 32; off; off >>= 1) {
        assoc += __shfl_down(assoc, off);
        cut   += __shfl_down(cut,  off);
    }
    if (l == 0) { red[2 * w] = assoc; red[2 * w + 1] = cut; }
    __syncthreads();
    if (t == 0) {
        float a = red[0] + red[2] + red[4] + red[6];
        float c = red[1] + red[3] + red[5] + red[7];
        atomicAdd(out, (c / (a + 1e-5f)) * (1.0f / 1024.0f));
    }
}

extern "C" void kernel_launch(void* const* d_in, const int* in_sizes, int n_in,
                              void* d_out, int out_size, void* d_ws, size_t ws_size,
                              hipStream_t stream)
{
    const float* pred = (const float*)d_in[0];   // (4,1,256,256) f32
    const float* feat = (const float*)d_in[1];   // (4,32,256,256) f32
    float* out = (float*)d_out;                  // scalar f32

    hipMemsetAsync(out, 0, sizeof(float) * out_size, stream);
    ncut_mfma_kernel<<<1024, 256, 0, stream>>>(pred, feat, out);
}

// Round 5
// 95.374 us; speedup vs baseline: 1.8744x; 1.2540x over previous
//
#include <hip/hip_runtime.h>
#include <stdint.h>

// NormalizedCutLoss via MFMA, round 5: tj-outer loop (no B-fragment register
// cache -> VGPR down, more waves/SIMD), exponent fused in log2 domain
// (5 ops/element incl. v_exp_f32), diagonal forced exact.

#define P2 256
#define CF 32
#define ROWP 40   // bf16 row pitch: 80B, keeps 16B alignment for b128 reads

using bf16x8 = __attribute__((ext_vector_type(8))) short;
using f32x4  = __attribute__((ext_vector_type(4))) float;

__device__ __forceinline__ short f2bf(float x) {
    union { float f; uint32_t u; } v; v.f = x;
    uint32_t r = (v.u + 0x7FFFu + ((v.u >> 16) & 1u)) >> 16;   // RNE
    return (short)r;
}

__global__ __launch_bounds__(256, 4)
void ncut_mfma_kernel(const float* __restrict__ pred,
                      const float* __restrict__ feat,
                      float* __restrict__ out)
{
    __shared__ short  fb[P2][ROWP];   // bf16 features [pixel][channel]
    __shared__ float2 sp[P2];         // {sq(f32), p}
    __shared__ float  red[8];

    const int t  = threadIdx.x;
    const int l  = t & 63;
    const int w  = t >> 6;
    const int b  = blockIdx.x;
    const int n  = b >> 8, pl = b & 255;
    const int hp = pl >> 4, wp = pl & 15;
    const int py = t >> 4,  px = t & 15;
    const int row = hp * 16 + py, col = wp * 16 + px;

    // ---- stage: 32 channels of own pixel -> bf16 LDS; sq in f32 ----
    const float* fbase = feat + (((size_t)n * CF) * 256 + row) * 256 + col;
    float sq = 0.f;
    short mybf[CF];
#pragma unroll
    for (int c = 0; c < CF; ++c) {
        float v = fbase[(size_t)c * 65536];
        sq = fmaf(v, v, sq);
        mybf[c] = f2bf(v);
    }
#pragma unroll
    for (int q = 0; q < 4; ++q)
        *(bf16x8*)&fb[t][q * 8] = *(const bf16x8*)&mybf[q * 8];
    const float p_i = pred[((size_t)n * 256 + row) * 256 + col];
    sp[t] = make_float2(sq, p_i);
    __syncthreads();

    const int lr = l & 15;   // col-in-tile (pixel j = tj*16+lr)
    const int lk = l >> 4;   // k-group; acc rows qi = lk*4+r

    // A-fragments for this wave's 4 row-tiles (ti = w*4+tii)
    bf16x8 af[4];
#pragma unroll
    for (int r = 0; r < 4; ++r)
        af[r] = *(const bf16x8*)&fb[(w * 4 + r) * 16 + lr][lk * 8];

    // log2-domain constants: exp(-50*dft - dsp/(2*16^2*255^2))
    //   = exp2(-L50*(sq_i+sq_j) + L100*dot + CSPL*dsp_px2)
    const float L50  = 72.134752f;      // 50*log2(e)
    const float L100 = 144.269504f;     // 100*log2(e)
    const float CSPL = -4.3333804e-8f;  // -log2(e)/(2*256*65025)

    // a[tii][r] = CSPL*(qi-lr)^2 - L50*sq_i   (pixel i = (w*4+tii)*16 + lk*4+r)
    float a[4][4];
    float api[4][4];
#pragma unroll
    for (int tii = 0; tii < 4; ++tii)
#pragma unroll
        for (int r = 0; r < 4; ++r) {
            const int qi = lk * 4 + r;
            const float dq = (float)(qi - lr);
            a[tii][r] = fmaf(dq * dq, CSPL, -L50 * sp[(w * 4 + tii) * 16 + qi].x);
            api[tii][r] = 0.f;
        }

    const f32x4 zero = {0.f, 0.f, 0.f, 0.f};
    const float tif = (float)(w * 4);

#pragma unroll 4
    for (int tj = 0; tj < 16; ++tj) {
        const bf16x8 bfj = *(const bf16x8*)&fb[tj * 16 + lr][lk * 8];
        const float2 spc = sp[tj * 16 + lr];          // {sq_j, p_j}
        const float bbase = -L50 * spc.x;
        const float tjf = (float)tj;
#pragma unroll
        for (int tii = 0; tii < 4; ++tii) {
            f32x4 acc = __builtin_amdgcn_mfma_f32_16x16x32_bf16(af[tii], bfj, zero, 0, 0, 0);
            const float dyf = tif + (float)tii - tjf;
            const float bj = fmaf(dyf * dyf, CSPL, bbase);
            const bool tdiag = (w * 4 + tii) == tj;
#pragma unroll
            for (int r = 0; r < 4; ++r) {
                float E2 = fmaf(L100, acc[r], a[tii][r] + bj);
                if (tdiag && (lk * 4 + r) == lr) E2 = 0.f;   // exact diagonal: A_ii=1
                api[tii][r] = fmaf(__builtin_amdgcn_exp2f(E2), spc.y, api[tii][r]);
            }
        }
    }

    // ---- reduce Ap over the 16 lanes sharing lk; then patch loss ----
    float assoc = 0.f, cut = 0.f;
#pragma unroll
    for (int tii = 0; tii < 4; ++tii)
#pragma unroll
        for (int r = 0; r < 4; ++r) {
            float v = api[tii][r];
            v += __shfl_xor(v, 1);
            v += __shfl_xor(v, 2);
            v += __shfl_xor(v, 4);
            v += __shfl_xor(v, 8);
            if (lr == 0) {
                const float pi = sp[(w * 4 + tii) * 16 + lk * 4 + r].y;
                assoc += v;
                cut   += (1.f - pi) * v;
            }
        }

#pragma unroll
    for (int off = 32; off; off >>= 1) {
        assoc += __shfl_down(assoc, off);
        cut   += __shfl_down(cut,  off);
    }
    if (l == 0) { red[2 * w] = assoc; red[2 * w + 1] = cut; }
    __syncthreads();
    if (t == 0) {
        float aa = red[0] + red[2] + red[4] + red[6];
        float cc = red[1] + red[3] + red[5] + red[7];
        atomicAdd(out, (cc / (aa + 1e-5f)) * (1.0f / 1024.0f));
    }
}

extern "C" void kernel_launch(void* const* d_in, const int* in_sizes, int n_in,
                              void* d_out, int out_size, void* d_ws, size_t ws_size,
                              hipStream_t stream)
{
    const float* pred = (const float*)d_in[0];   // (4,1,256,256) f32
    const float* feat = (const float*)d_in[1];   // (4,32,256,256) f32
    float* out = (float*)d_out;                  // scalar f32

    hipMemsetAsync(out, 0, sizeof(float) * out_size, stream);
    ncut_mfma_kernel<<<1024, 256, 0, stream>>>(pred, feat, out);
}